// Round 1
// baseline (802.775 us; speedup 1.0000x reference)
//
#include <hip/hip_runtime.h>

typedef __attribute__((ext_vector_type(8))) _Float16 half8;
typedef __attribute__((ext_vector_type(16))) float f32x16;

// Region tables (compile-time constants from the reference)
static __device__ const int d_LENS[14] = {4,3,2,1,2,3,2,3,2,1,1,3,2,3};
static __device__ const int d_RIDX[14][4] = {
  {0,1,16,17},{2,18,19,19},{3,4,4,4},{20,20,20,20},{7,8,8,8},{21,25,26,26},
  {5,22,22,22},{6,23,24,24},{9,27,27,27},{11,11,11,11},{29,29,29,29},
  {10,15,28,28},{12,30,30,30},{13,14,31,31}};

__device__ __forceinline__ float sigf(float v){
  return __builtin_amdgcn_rcpf(1.0f + __expf(-v));
}
__device__ __forceinline__ float tanhf2(float v){
  return 1.0f - 2.0f*__builtin_amdgcn_rcpf(1.0f + __expf(2.0f*v));
}

// ---------------------------------------------------------------------------
// prep: f32 -> f16 weights with gate-interleave row permutation, fused biases.
// n' = c*256 + u*128 + gate*32 + v  <->  n = gate*128 + (u*64 + c*32 + v)
// ---------------------------------------------------------------------------
__global__ void prep_k(const float* __restrict__ w_ih, const float* __restrict__ w_hh,
                       const float* __restrict__ b_ih, const float* __restrict__ b_hh,
                       _Float16* __restrict__ wih, _Float16* __restrict__ whh,
                       float* __restrict__ bias)
{
  int tid = blockIdx.x*256 + threadIdx.x;
  if (tid < 2*1835008){
    const float* src = (tid < 1835008) ? w_ih : w_hh;
    _Float16* dst    = (tid < 1835008) ? wih  : whh;
    int t  = (tid < 1835008) ? tid : (tid - 1835008);
    int k  = t & 127;
    int np = (t >> 7) & 511;
    int rd = t >> 16;                 // r*2+d, 0..27
    int c = (np >> 8) & 1, uu = (np >> 7) & 1, gate = (np >> 5) & 3, vv = np & 31;
    int n = gate*128 + uu*64 + c*32 + vv;
    dst[t] = (_Float16)src[((size_t)rd*512 + n)*128 + k];
  } else {
    int t = tid - 2*1835008;
    if (t < 14336){
      int rd = t >> 9, np = t & 511;
      int c = (np >> 8) & 1, uu = (np >> 7) & 1, gate = (np >> 5) & 3, vv = np & 31;
      int n = gate*128 + uu*64 + c*32 + vv;
      bias[t] = b_ih[rd*512 + n] + b_hh[rd*512 + n];
    }
  }
}

// ---------------------------------------------------------------------------
// Main fused LSTM kernel. Block = (btile of 128 rows, region). 512 thr/8 waves.
// Wave wv: row-group wr=wv>>1 (32 rows), col-half u=wv&1 (128 of 512 gate cols).
// LDS: wbuf [256][128] f16 (64KB, one weight chunk, XOR-swizzled rows),
//      hbuf [128][128] f16 (32KB, recurrent h, XOR-swizzled rows).
// ---------------------------------------------------------------------------
__global__ __launch_bounds__(512, 2) void lstm_k(
    const float* __restrict__ x, const _Float16* __restrict__ wih,
    const _Float16* __restrict__ whh, const float* __restrict__ bias,
    float* __restrict__ out, float* __restrict__ part)
{
  extern __shared__ char smem[];
  _Float16* wbuf = (_Float16*)smem;                 // 64 KB
  _Float16* hbuf = (_Float16*)(smem + 65536);       // 32 KB
  float* red = (float*)(smem + 65536);              // alias, used only at end

  const int tid  = threadIdx.x;
  const int lane = tid & 63;
  const int wv = tid >> 6;
  const int wr = wv >> 1;
  const int u  = wv & 1;
  const int v  = lane & 31;
  const int q  = lane >> 5;

  const int r  = blockIdx.y;
  const int b0 = blockIdx.x << 7;
  const int len = d_LENS[r];

  float bf0[2][4];
  #pragma unroll
  for (int c=0;c<2;c++)
    #pragma unroll
    for (int g=0;g<4;g++)
      bf0[c][g] = bias[(size_t)r*1024 + c*256 + u*128 + g*32 + v];

  f32x16 acc[2][4];
  float cst[2][16];
  float hfin[2][16];
  #pragma unroll
  for (int c=0;c<2;c++)
    #pragma unroll
    for (int e=0;e<16;e++) cst[c][e] = 0.0f;

  for (int t=0; t<len; ++t){
    const int chan = d_RIDX[r][t];
    #pragma unroll
    for (int c=0;c<2;c++)
      #pragma unroll
      for (int g=0;g<4;g++)
        #pragma unroll
        for (int e=0;e<16;e++) acc[c][g][e] = bf0[c][g];

    // ---- x_t * W_ih (K=128), chunked over the two 256-col halves ----
    #pragma unroll
    for (int c=0;c<2;c++){
      __syncthreads();
      {
        const _Float16* src = wih + (((size_t)r*2)*512 + c*256)*128;
        #pragma unroll
        for (int i=0;i<8;i++){
          int e = tid + i*512;
          int n = e >> 4, s = e & 15;
          uint4 dd = *(const uint4*)(src + e*8);
          *(uint4*)((char*)wbuf + ((n*256 + s*16) ^ ((n&7)<<4))) = dd;
        }
      }
      __syncthreads();
      const float* xbase = x + (((size_t)(b0 + wr*32 + v))*32 + chan)*128 + q*8;
      #pragma unroll
      for (int ks=0;ks<8;ks++){
        const float* xp = xbase + ks*16;
        float4 a0 = *(const float4*)xp;
        float4 a1 = *(const float4*)(xp+4);
        half8 a;
        a[0]=(_Float16)a0.x; a[1]=(_Float16)a0.y; a[2]=(_Float16)a0.z; a[3]=(_Float16)a0.w;
        a[4]=(_Float16)a1.x; a[5]=(_Float16)a1.y; a[6]=(_Float16)a1.z; a[7]=(_Float16)a1.w;
        #pragma unroll
        for (int g=0;g<4;g++){
          int nl = u*128 + g*32 + v;
          half8 bb = *(const half8*)((char*)wbuf + ((nl*256 + ks*32 + q*16) ^ ((nl&7)<<4)));
          acc[c][g] = __builtin_amdgcn_mfma_f32_32x32x16_f16(a, bb, acc[c][g], 0, 0, 0);
        }
      }
    }
    // ---- h_{t-1} * W_hh (skipped at t=0 since h0=0) ----
    if (t > 0){
      #pragma unroll
      for (int c=0;c<2;c++){
        __syncthreads();
        {
          const _Float16* src = whh + (((size_t)r*2)*512 + c*256)*128;
          #pragma unroll
          for (int i=0;i<8;i++){
            int e = tid + i*512;
            int n = e >> 4, s = e & 15;
            uint4 dd = *(const uint4*)(src + e*8);
            *(uint4*)((char*)wbuf + ((n*256 + s*16) ^ ((n&7)<<4))) = dd;
          }
        }
        __syncthreads();
        const int hrow = wr*32 + v;
        #pragma unroll
        for (int ks=0;ks<8;ks++){
          half8 a = *(const half8*)((char*)hbuf + ((hrow*256 + ks*32 + q*16) ^ ((hrow&7)<<4)));
          #pragma unroll
          for (int g=0;g<4;g++){
            int nl = u*128 + g*32 + v;
            half8 bb = *(const half8*)((char*)wbuf + ((nl*256 + ks*32 + q*16) ^ ((nl&7)<<4)));
            acc[c][g] = __builtin_amdgcn_mfma_f32_32x32x16_f16(a, bb, acc[c][g], 0, 0, 0);
          }
        }
      }
    }
    const bool last = (t == len-1);
    if (t > 0 && !last) __syncthreads();   // pair wave may still read hbuf rows
    #pragma unroll
    for (int c=0;c<2;c++)
      #pragma unroll
      for (int e=0;e<16;e++){
        float iv = acc[c][0][e], fv = acc[c][1][e];
        float gv = acc[c][2][e], ov = acc[c][3][e];
        float cn = sigf(iv)*tanhf2(gv) + sigf(fv)*cst[c][e];
        cst[c][e] = cn;
        float hv = sigf(ov)*tanhf2(cn);
        if (last) hfin[c][e] = hv;
        else {
          int row = wr*32 + (e&3) + ((e>>2)<<3) + (q<<2);
          *(_Float16*)((char*)hbuf + ((row*256 + (u*64 + c*32 + v)*2) ^ ((row&7)<<4)))
              = (_Float16)hv;
        }
      }
  }

  // ---- backward single cell: h0=c0=0 -> gates = x_last*W_ih[,1] + bb ----
  {
    const int chan = d_RIDX[r][len-1];
    #pragma unroll
    for (int c=0;c<2;c++)
      #pragma unroll
      for (int g=0;g<4;g++){
        float bv = bias[(size_t)r*1024 + 512 + c*256 + u*128 + g*32 + v];
        #pragma unroll
        for (int e=0;e<16;e++) acc[c][g][e] = bv;
      }
    #pragma unroll
    for (int c=0;c<2;c++){
      __syncthreads();
      {
        const _Float16* src = wih + (((size_t)r*2 + 1)*512 + c*256)*128;
        #pragma unroll
        for (int i=0;i<8;i++){
          int e = tid + i*512;
          int n = e >> 4, s = e & 15;
          uint4 dd = *(const uint4*)(src + e*8);
          *(uint4*)((char*)wbuf + ((n*256 + s*16) ^ ((n&7)<<4))) = dd;
        }
      }
      __syncthreads();
      const float* xbase = x + (((size_t)(b0 + wr*32 + v))*32 + chan)*128 + q*8;
      #pragma unroll
      for (int ks=0;ks<8;ks++){
        const float* xp = xbase + ks*16;
        float4 a0 = *(const float4*)xp;
        float4 a1 = *(const float4*)(xp+4);
        half8 a;
        a[0]=(_Float16)a0.x; a[1]=(_Float16)a0.y; a[2]=(_Float16)a0.z; a[3]=(_Float16)a0.w;
        a[4]=(_Float16)a1.x; a[5]=(_Float16)a1.y; a[6]=(_Float16)a1.z; a[7]=(_Float16)a1.w;
        #pragma unroll
        for (int g=0;g<4;g++){
          int nl = u*128 + g*32 + v;
          half8 bb = *(const half8*)((char*)wbuf + ((nl*256 + ks*32 + q*16) ^ ((nl&7)<<4)));
          acc[c][g] = __builtin_amdgcn_mfma_f32_32x32x16_f16(a, bb, acc[c][g], 0, 0, 0);
        }
      }
    }
  }

  // ---- outputs (raw, pre-LN) + per-block partial sums ----
  float lsum = 0.0f, lsq = 0.0f;
  #pragma unroll
  for (int c=0;c<2;c++)
    #pragma unroll
    for (int e=0;e<16;e++){
      float iv = acc[c][0][e];
      float gv = acc[c][2][e], ov = acc[c][3][e];
      float cn = sigf(iv)*tanhf2(gv);
      float hb = sigf(ov)*tanhf2(cn);
      float hf = hfin[c][e];
      int row = b0 + wr*32 + (e&3) + ((e>>2)<<3) + (q<<2);
      int col = u*64 + c*32 + v;
      size_t base = ((size_t)row*14 + r)*256 + col;
      out[base] = hf;
      out[base + 128] = hb;
      lsum += hf + hb;
      lsq  += hf*hf + hb*hb;
    }
  #pragma unroll
  for (int off=32; off>0; off>>=1){
    lsum += __shfl_down(lsum, off);
    lsq  += __shfl_down(lsq, off);
  }
  __syncthreads();
  if (lane == 0){ red[wv] = lsum; red[8+wv] = lsq; }
  __syncthreads();
  if (tid == 0){
    float s = 0.0f, s2 = 0.0f;
    #pragma unroll
    for (int w=0;w<8;w++){ s += red[w]; s2 += red[8+w]; }
    part[((size_t)r*64 + blockIdx.x)*2]     = s;
    part[((size_t)r*64 + blockIdx.x)*2 + 1] = s2;
  }
}

// ---------------------------------------------------------------------------
__global__ void stats_k(const float* __restrict__ part, const float* __restrict__ gamma,
                        const float* __restrict__ beta, float* __restrict__ stat)
{
  int r = blockIdx.x, l = threadIdx.x;      // 14 blocks x 64 threads
  float s  = part[((size_t)r*64 + l)*2];
  float s2 = part[((size_t)r*64 + l)*2 + 1];
  #pragma unroll
  for (int off=32; off>0; off>>=1){ s += __shfl_down(s, off); s2 += __shfl_down(s2, off); }
  if (l == 0){
    const float cnt = 2097152.0f;           // B * 2H
    float m = s / cnt;
    float var = s2 / cnt - m*m;
    float rstd = rsqrtf(var + 1e-5f);
    float sc = gamma[r]*rstd;
    stat[r*2]   = sc;
    stat[r*2+1] = beta[r] - m*sc;
  }
}

__global__ void apply_k(float* __restrict__ out, const float* __restrict__ stat)
{
  size_t idx = (size_t)blockIdx.x*256 + threadIdx.x;   // one float4 each
  float4* p = (float4*)out + idx;
  float4 vv = *p;
  int r = (int)((idx >> 6) % 14);
  float sc = stat[r*2], sh = stat[r*2+1];
  vv.x = vv.x*sc + sh; vv.y = vv.y*sc + sh; vv.z = vv.z*sc + sh; vv.w = vv.w*sc + sh;
  *p = vv;
}

// ---------------------------------------------------------------------------
extern "C" void kernel_launch(void* const* d_in, const int* in_sizes, int n_in,
                              void* d_out, int out_size, void* d_ws, size_t ws_size,
                              hipStream_t stream)
{
  const float* x     = (const float*)d_in[0];
  const float* w_ih  = (const float*)d_in[1];
  const float* w_hh  = (const float*)d_in[2];
  const float* b_ih  = (const float*)d_in[3];
  const float* b_hh  = (const float*)d_in[4];
  const float* gamma = (const float*)d_in[5];
  const float* beta  = (const float*)d_in[6];
  float* out = (float*)d_out;

  _Float16* wih = (_Float16*)d_ws;          // 1,835,008 f16
  _Float16* whh = wih + 1835008;            // 1,835,008 f16
  float* bias = (float*)(whh + 1835008);    // 14,336 f32 (fused b_ih+b_hh, both dirs)
  float* part = bias + 14336;               // 896*2 f32 partials
  float* stat = part + 1792;                // 14*2 f32 (scale, shift)

  prep_k<<<14392, 256, 0, stream>>>(w_ih, w_hh, b_ih, b_hh, wih, whh, bias);
  lstm_k<<<dim3(64,14), 512, 98304, stream>>>(x, wih, whh, bias, out, part);
  stats_k<<<14, 64, 0, stream>>>(part, gamma, beta, stat);
  apply_k<<<28672, 256, 0, stream>>>(out, stat);
}